// Round 10
// baseline (72.399 us; speedup 1.0000x reference)
//
#include <hip/hip_runtime.h>
#include <cstdint>
#include <cstddef>

// Reference semantics: per-element fp32-rounded multiply, then a strictly
// sequential left-to-right fp32 add chain. FMA contraction changes low
// mantissa bits and flips output pulse bits -> keep contract OFF globally.
#pragma clang fp contract(off)

#define BATCH 256
#define IN_F  1024
#define OUT_F 1024

// ---------------------------------------------------------------------------
// Ballot decode (R9, proven): one wave decodes 64 consecutive values/chunk.
// Chunks [0,4096): x -> xf[b][i] row-major.
// Chunks [4096,20480): w -> wt3 [IN/4][OUT][4] fp32: element (o,i) at
// dword ((i>>2)*1024 + o)*4 + (i&3). This makes the gemm's staging source
// for one 4-i segment x 64 o a CONTIGUOUS 1024 B block.
// ---------------------------------------------------------------------------
__global__ __launch_bounds__(256) void decode_kernel(const float* __restrict__ xp,
                                                     const float* __restrict__ wp,
                                                     float* __restrict__ xf,
                                                     float* __restrict__ wt3) {
    const int tid  = threadIdx.x;
    const int lane = tid & 63;
    const int wv   = tid >> 6;
    const int chunk = blockIdx.x * 4 + wv;         // global wave-chunk

    uint32_t val = 0;
    if (chunk < 4096) {
        const size_t v0 = (size_t)chunk * 64;      // first value index
        const float* src = xp + v0 * 32 + lane;
#pragma unroll
        for (int t = 0; t < 32; ++t) {
            uint32_t u = __float_as_uint(src[t * 64]);
            uint64_t m = __ballot(u & 0x00800000u);        // bit23: 1.0f vs 0.0f
            uint32_t lo = __builtin_bitreverse32((uint32_t)m);
            uint32_t hi = __builtin_bitreverse32((uint32_t)(m >> 32));
            uint32_t pick = (lane & 1) ? hi : lo;
            if ((lane >> 1) == t) val = pick;
        }
        xf[v0 + lane] = __uint_as_float(val);      // coalesced 256 B
    } else {
        const int c = chunk - 4096;                // 0..16383
        const size_t v0 = (size_t)c * 64;          // = o*1024 + i0 (i0 % 64 == 0)
        const float* src = wp + v0 * 32 + lane;
#pragma unroll
        for (int t = 0; t < 32; ++t) {
            uint32_t u = __float_as_uint(src[t * 64]);
            uint64_t m = __ballot(u & 0x00800000u);
            uint32_t lo = __builtin_bitreverse32((uint32_t)m);
            uint32_t hi = __builtin_bitreverse32((uint32_t)(m >> 32));
            uint32_t pick = (lane & 1) ? hi : lo;
            if ((lane >> 1) == t) val = pick;
        }
        const int o = (int)(v0 >> 10);             // constant across wave
        const int i = (int)(v0 & 1023) + lane;
        size_t idx = ((size_t)(i >> 2) * 1024 + o) * 4 + (i & 3);
        wt3[idx] = __uint_as_float(val);
    }
}

// ---------------------------------------------------------------------------
// GEMM: block = 512 threads = 8 waves; 64 o (lanes) x 16 b rows (wave wv
// handles rows wv and wv+8). Grid = 256 blocks = 1 per CU.
// LDS FIX (R10): layout [32 seg][64 o] float4 per 128-i chunk. Reads are the
// canonical linear pattern base + lane*16 (m134 fast case) — the old
// [o][slot] layout had 128-B row stride = all rows bank-aligned, so lanes
// {l, l+8, ...} hit the same bank-quad at different rows on EVERY
// ds_read_b128 (hidden multi-way conflict; R4-R7's unexplained ~3x).
// Staging: global_load_lds, source contiguous 1024 B per (wave, segment).
// x delivered via v_readlane from per-lane dwords (proven R6).
// Strict left-to-right fp32 accumulation over i; mul then add, no FMA.
// ---------------------------------------------------------------------------
__global__ __launch_bounds__(512, 1) void gemm_encode_kernel(const float* __restrict__ xf,
                                                             const float* __restrict__ wt3,
                                                             float* __restrict__ out) {
#pragma clang fp contract(off)
    const int tid  = threadIdx.x;
    const int lane = tid & 63;
    const int wv   = tid >> 6;
    const int ot   = blockIdx.x & 15;              // o-tile
    const int bt   = blockIdx.x >> 4;              // b-tile
    const int o_g  = ot * 64 + lane;
    const int b0   = bt * 16;

    __shared__ float4 wl[2][32][64];               // 64 KB: [buf][seg][o]

    const float* __restrict__ xr0 = xf + ((size_t)(b0 + wv) << 10);
    const float* __restrict__ xr1 = xf + ((size_t)(b0 + wv + 8) << 10);

    // stage one 128-i chunk: 32 segments x 1024 B; wave wv does segments
    // r*8+wv, r=0..3; lane l fetches (o = ot*64+l)'s 16 B for that segment.
    auto stage = [&](int bb, int c) {
#pragma unroll
        for (int r = 0; r < 4; ++r) {
            const int seg = r * 8 + wv;
            const size_t dw = ((size_t)(c * 32 + seg) * 1024 + (ot * 64)) * 4;
            const char* g = (const char*)(wt3 + dw) + lane * 16;
            char* d = (char*)(&wl[bb][seg][0]);    // wave-uniform; +lane*16 implicit
            __builtin_amdgcn_global_load_lds(
                (const __attribute__((address_space(1))) void*)g,
                (__attribute__((address_space(3))) void*)d, 16, 0, 0);
        }
    };

    float acc0 = 0.0f, acc1 = 0.0f;

    // xa* hold i = chunk*128 + [0,64) at lane = i; xb* hold i = +[64,128).
    auto compute = [&](int bb, float xa0, float xb0, float xa1, float xb1, bool first) {
#pragma unroll
        for (int seg = 0; seg < 32; ++seg) {
            float4 w4 = wl[bb][seg][lane];         // linear: conflict-free
            const float wq[4] = {w4.x, w4.y, w4.z, w4.w};
#pragma unroll
            for (int d = 0; d < 4; ++d) {
                const int il = seg * 4 + d;        // i within chunk (ascending)
                const int ll = il & 63;            // literal lane index
                const bool loh = (il < 64);
                float x0 = __uint_as_float(__builtin_amdgcn_readlane(
                    __float_as_uint(loh ? xa0 : xb0), ll));
                float x1 = __uint_as_float(__builtin_amdgcn_readlane(
                    __float_as_uint(loh ? xa1 : xb1), ll));
                if (first && seg == 0 && d == 0) {
                    acc0 = x0 * wq[0];             // scan init: acc = prods[0]
                    acc1 = x1 * wq[0];
                } else {
                    acc0 = acc0 + (x0 * wq[d]);
                    acc1 = acc1 + (x1 * wq[d]);
                }
            }
        }
    };

    // prologue: stage chunk 0 (w) and load chunk 0's x registers
    stage(0, 0);
    float xa0 = xr0[lane], xb0 = xr0[64 + lane];
    float xa1 = xr1[lane], xb1 = xr1[64 + lane];
    __syncthreads();                                // drains vmcnt before use

    int cur = 0;
#pragma unroll 1
    for (int c = 0; c < 8; ++c) {
        float na0 = 0.f, nb0 = 0.f, na1 = 0.f, nb1 = 0.f;
        if (c < 7) {
            stage(cur ^ 1, c + 1);                  // issue next w-chunk loads
            const int off = (c + 1) << 7;           // and next x-chunk loads
            na0 = xr0[off + lane]; nb0 = xr0[off + 64 + lane];
            na1 = xr1[off + lane]; nb1 = xr1[off + 64 + lane];
        }
        compute(cur, xa0, xb0, xa1, xb1, c == 0);
        __syncthreads();                            // vmcnt+lgkm drain + barrier
        xa0 = na0; xb0 = nb0; xa1 = na1; xb1 = nb1;
        cur ^= 1;
    }

    // ---- encode both accumulators back to 32 pulse floats ----
    const float accs[2] = {acc0, acc1};
#pragma unroll
    for (int r = 0; r < 2; ++r) {
        uint32_t u = __float_as_uint(accs[r]);
        int b = b0 + wv + r * 8;
        float4* dstp = (float4*)(out + (((size_t)b << 10) + o_g) * 32);
#pragma unroll
        for (int k = 0; k < 8; ++k) {
            float4 f;
            f.x = (float)((u >> (31 - 4 * k)) & 1u);
            f.y = (float)((u >> (30 - 4 * k)) & 1u);
            f.z = (float)((u >> (29 - 4 * k)) & 1u);
            f.w = (float)((u >> (28 - 4 * k)) & 1u);
            dstp[k] = f;
        }
    }
}

extern "C" void kernel_launch(void* const* d_in, const int* in_sizes, int n_in,
                              void* d_out, int out_size, void* d_ws, size_t ws_size,
                              hipStream_t stream) {
    const float* x_pulses = (const float*)d_in[0];   // [B, IN, 32]
    const float* w_pulses = (const float*)d_in[1];   // [OUT, IN, 32]
    float* out = (float*)d_out;                      // [B, OUT, 32]

    float* xf  = (float*)d_ws;                       // xf[B][IN]      : 1 MB
    float* wt3 = xf + (size_t)BATCH * IN_F;          // wt3[IN/4][O][4]: 4 MB

    decode_kernel<<<5120, 256, 0, stream>>>(x_pulses, w_pulses, xf, wt3);
    gemm_encode_kernel<<<256, 512, 0, stream>>>(xf, wt3, out);
}